// Round 2
// 696.969 us; speedup vs baseline: 1.1047x; 1.1047x over previous
//
#include <hip/hip_runtime.h>

// BlockXDiag forward: 64 GEMMs of [4096 x 768] x [768 x 256] (periodic block-tridiag).
// V2 (resubmit after infra failure): pre-convert x and W to bf16 in workspace
// (one conversion per element), then m97-style bf16 GEMM with global_load_lds
// width-16 staging (no VALU conversion in the hot loop). Falls back to the V1
// fp32-staging kernel if the workspace is too small.

#define MB   64      // blocks per row/col
#define PB   256     // block size
#define NPR  16384   // MB*PB, row stride of x/out
#define BSZ  4096    // batch
#define BM   128
#define BN   128
#define BK   32
#define KTOT 768     // 3 * PB

typedef __bf16 bf16x8 __attribute__((ext_vector_type(8)));
typedef float  f32x4  __attribute__((ext_vector_type(4)));
typedef unsigned short u16x4 __attribute__((ext_vector_type(4)));
typedef unsigned short u16x8 __attribute__((ext_vector_type(8)));

__device__ __forceinline__ unsigned short f2bf(float f) {
    unsigned u = __float_as_uint(f);
    u += 0x7fffu + ((u >> 16) & 1u);   // round-to-nearest-even
    return (unsigned short)(u >> 16);
}

__device__ __forceinline__ void gload_lds16(const void* g, void* l) {
    __builtin_amdgcn_global_load_lds(
        (const __attribute__((address_space(1))) void*)g,
        (__attribute__((address_space(3))) void*)l, 16, 0, 0);
}

// ---------------- conversion pass 1: x (f32) -> xb (bf16) -------------------
__global__ __launch_bounds__(256)
void cvt_x(const float* __restrict__ in, __bf16* __restrict__ o, int n8) {
    int idx    = blockIdx.x * 256 + threadIdx.x;
    int stride = gridDim.x * 256;
    for (; idx < n8; idx += stride) {
        const float4* p = (const float4*)in + (size_t)idx * 2;
        float4 a = p[0], b = p[1];
        u16x8 r = { f2bf(a.x), f2bf(a.y), f2bf(a.z), f2bf(a.w),
                    f2bf(b.x), f2bf(b.y), f2bf(b.z), f2bf(b.w) };
        *((u16x8*)o + idx) = r;
    }
}

// -------- conversion pass 2: gather W into wcat[i][c][n][k] (bf16) ----------
// c=0: prev-block weight (Wtr for i=0 else Wl[i-1]); c=1: Wd[i];
// c=2: next-block weight (Wbl for i=M-1 else Wu[i]).
__global__ __launch_bounds__(256)
void cvt_w(const float* __restrict__ Wd, const float* __restrict__ Wu,
           const float* __restrict__ Wl, const float* __restrict__ Wtr,
           const float* __restrict__ Wbl, __bf16* __restrict__ wcat) {
    const int i = blockIdx.y;
    const int c = blockIdx.z;
    const float* src;
    if      (c == 0) src = (i == 0)      ? Wtr : Wl + (size_t)(i - 1) * (PB * PB);
    else if (c == 1) src = Wd + (size_t)i * (PB * PB);
    else             src = (i == MB - 1) ? Wbl : Wu + (size_t)i * (PB * PB);

    const int off = (blockIdx.x * 256 + threadIdx.x) * 8;
    const float4* p = (const float4*)(src + off);
    float4 a = p[0], b = p[1];
    u16x8 r = { f2bf(a.x), f2bf(a.y), f2bf(a.z), f2bf(a.w),
                f2bf(b.x), f2bf(b.y), f2bf(b.z), f2bf(b.w) };
    *(u16x8*)(wcat + (size_t)(i * 3 + c) * (PB * PB) + off) = r;
}

// ---------------- main bf16 GEMM (m97 structure) ----------------------------
__global__ __launch_bounds__(256, 4)
void bxd_bf16(const __bf16* __restrict__ xb, const __bf16* __restrict__ wcat,
              float* __restrict__ out)
{
    __shared__ __bf16 sA[BM * BK];   // [row][k], linear (global_load_lds dest)
    __shared__ __bf16 sB[BN * BK];   // [n][k]

    const int i  = blockIdx.x >> 1;   // output block column 0..63
    const int nt = blockIdx.x & 1;    // n-tile within block (2 x 128)
    const int mt = blockIdx.y;        // m-tile (32 x 128)

    const int t    = threadIdx.x;
    const int lane = t & 63;
    const int wave = t >> 6;
    const int wm   = wave & 1;
    const int wn   = wave >> 1;
    const int quad = lane >> 4;
    const int l16  = lane & 15;

    const int jblk[3] = { (i + MB - 1) & (MB - 1), i, (i + 1) & (MB - 1) };

    // staging: chunk = t + p*256 of 512 16B-chunks; row = chunk>>2, kc = (chunk&3)*8
    const int row0 = t >> 2;          // 0..63 (p adds 64)
    const int kc   = (t & 3) * 8;     // bf16 k-offset within BK

    f32x4 acc[4][4];
    #pragma unroll
    for (int a = 0; a < 4; ++a)
        #pragma unroll
        for (int b = 0; b < 4; ++b)
            acc[a][b] = (f32x4){0.f, 0.f, 0.f, 0.f};

    for (int kt = 0; kt < KTOT / BK; ++kt) {
        const int c  = kt >> 3;       // which P-chunk (0..2)
        const int kb = kt & 7;        // BK-tile within chunk

        const __bf16* aBase = xb + (size_t)(mt * BM) * NPR + jblk[c] * PB + kb * BK;
        const __bf16* bBase = wcat + (size_t)(i * 3 + c) * (PB * PB)
                                   + (size_t)(nt * BN) * PB + kb * BK;

        __syncthreads();   // previous iter's LDS reads complete before overwrite
        #pragma unroll
        for (int p = 0; p < 2; ++p) {
            const int r = row0 + p * 64;
            gload_lds16(aBase + (size_t)r * NPR + kc, &sA[(t + p * 256) * 8]);
            gload_lds16(bBase + (size_t)r * PB  + kc, &sB[(t + p * 256) * 8]);
        }
        __syncthreads();   // vmcnt drained at barrier -> tile visible

        bf16x8 afrag[4], bfrag[4];
        #pragma unroll
        for (int mi = 0; mi < 4; ++mi)
            afrag[mi] = *(const bf16x8*)&sA[(wm * 64 + mi * 16 + l16) * BK + quad * 8];
        #pragma unroll
        for (int ni = 0; ni < 4; ++ni)
            bfrag[ni] = *(const bf16x8*)&sB[(wn * 64 + ni * 16 + l16) * BK + quad * 8];

        #pragma unroll
        for (int mi = 0; mi < 4; ++mi)
            #pragma unroll
            for (int ni = 0; ni < 4; ++ni)
                acc[mi][ni] = __builtin_amdgcn_mfma_f32_16x16x32_bf16(
                    afrag[mi], bfrag[ni], acc[mi][ni], 0, 0, 0);
    }

    // epilogue: C/D layout col = lane&15 (n), row = quad*4 + reg (m)
    const int colb = i * PB + nt * BN + wn * 64;
    #pragma unroll
    for (int mi = 0; mi < 4; ++mi) {
        #pragma unroll
        for (int ni = 0; ni < 4; ++ni) {
            #pragma unroll
            for (int r = 0; r < 4; ++r) {
                const int row = mt * BM + wm * 64 + mi * 16 + quad * 4 + r;
                out[(size_t)row * NPR + colb + ni * 16 + l16] = acc[mi][ni][r];
            }
        }
    }
}

// ---------------- V1 fallback (fp32 staging, verified) ----------------------
__global__ __launch_bounds__(256, 2)
void bxd_kernel(const float* __restrict__ x,
                const float* __restrict__ Wd,
                const float* __restrict__ Wu,
                const float* __restrict__ Wl,
                const float* __restrict__ Wtr,
                const float* __restrict__ Wbl,
                float* __restrict__ out)
{
    __shared__ unsigned short sA[BM * BK];
    __shared__ unsigned short sB[BN * BK];

    const int i  = blockIdx.x >> 1;
    const int nt = blockIdx.x & 1;
    const int mt = blockIdx.y;

    const int t    = threadIdx.x;
    const int lane = t & 63;
    const int wave = t >> 6;
    const int wm   = wave & 1;
    const int wn   = wave >> 1;
    const int quad = lane >> 4;
    const int l16  = lane & 15;

    const int srow = t >> 3;
    const int scol = (t & 7) * 4;

    const float* wptr[3];
    wptr[0] = (i == 0)      ? Wtr : (Wl + (size_t)(i - 1) * (PB * PB));
    wptr[1] = Wd + (size_t)i * (PB * PB);
    wptr[2] = (i == MB - 1) ? Wbl : (Wu + (size_t)i * (PB * PB));
    const int jblk[3] = { (i + MB - 1) & (MB - 1), i, (i + 1) & (MB - 1) };

    f32x4 acc[4][4];
    #pragma unroll
    for (int a = 0; a < 4; ++a)
        #pragma unroll
        for (int b = 0; b < 4; ++b)
            acc[a][b] = (f32x4){0.f, 0.f, 0.f, 0.f};

    for (int kt = 0; kt < KTOT / BK; ++kt) {
        const int c  = kt >> 3;
        const int kb = kt & 7;

        const float* aSrc = x + (size_t)(mt * BM + srow) * NPR
                              + jblk[c] * PB + kb * BK + scol;
        const float* bSrc = wptr[c] + (size_t)(nt * BN + srow) * PB
                              + kb * BK + scol;

        float4 av[4], bv[4];
        #pragma unroll
        for (int p = 0; p < 4; ++p) {
            av[p] = *(const float4*)(aSrc + (size_t)p * 32 * NPR);
            bv[p] = *(const float4*)(bSrc + (size_t)p * 32 * PB);
        }

        __syncthreads();
        #pragma unroll
        for (int p = 0; p < 4; ++p) {
            u16x4 ra = { f2bf(av[p].x), f2bf(av[p].y), f2bf(av[p].z), f2bf(av[p].w) };
            *(u16x4*)&sA[(srow + p * 32) * BK + scol] = ra;
            u16x4 rb = { f2bf(bv[p].x), f2bf(bv[p].y), f2bf(bv[p].z), f2bf(bv[p].w) };
            *(u16x4*)&sB[(srow + p * 32) * BK + scol] = rb;
        }
        __syncthreads();

        bf16x8 afrag[4], bfrag[4];
        #pragma unroll
        for (int mi = 0; mi < 4; ++mi)
            afrag[mi] = *(const bf16x8*)&sA[(wm * 64 + mi * 16 + l16) * BK + quad * 8];
        #pragma unroll
        for (int ni = 0; ni < 4; ++ni)
            bfrag[ni] = *(const bf16x8*)&sB[(wn * 64 + ni * 16 + l16) * BK + quad * 8];

        #pragma unroll
        for (int mi = 0; mi < 4; ++mi)
            #pragma unroll
            for (int ni = 0; ni < 4; ++ni)
                acc[mi][ni] = __builtin_amdgcn_mfma_f32_16x16x32_bf16(
                    afrag[mi], bfrag[ni], acc[mi][ni], 0, 0, 0);
    }

    const int colb = i * PB + nt * BN + wn * 64;
    #pragma unroll
    for (int mi = 0; mi < 4; ++mi) {
        #pragma unroll
        for (int ni = 0; ni < 4; ++ni) {
            #pragma unroll
            for (int r = 0; r < 4; ++r) {
                const int row = mt * BM + wm * 64 + mi * 16 + quad * 4 + r;
                out[(size_t)row * NPR + colb + ni * 16 + l16] = acc[mi][ni][r];
            }
        }
    }
}

extern "C" void kernel_launch(void* const* d_in, const int* in_sizes, int n_in,
                              void* d_out, int out_size, void* d_ws, size_t ws_size,
                              hipStream_t stream) {
    const float* x   = (const float*)d_in[0];
    const float* Wd  = (const float*)d_in[1];
    const float* Wu  = (const float*)d_in[2];
    const float* Wl  = (const float*)d_in[3];
    const float* Wtr = (const float*)d_in[4];
    const float* Wbl = (const float*)d_in[5];
    float* out = (float*)d_out;

    const size_t xbytes = (size_t)BSZ * NPR * sizeof(__bf16);        // 128 MiB
    const size_t wbytes = (size_t)MB * 3 * PB * PB * sizeof(__bf16); // 24 MiB

    if (ws_size >= xbytes + wbytes) {
        __bf16* xbuf = (__bf16*)d_ws;
        __bf16* wcat = (__bf16*)((char*)d_ws + xbytes);
        hipLaunchKernelGGL(cvt_x, dim3(2048), dim3(256), 0, stream,
                           x, xbuf, (int)((size_t)BSZ * NPR / 8));
        hipLaunchKernelGGL(cvt_w, dim3(32, 64, 3), dim3(256), 0, stream,
                           Wd, Wu, Wl, Wtr, Wbl, wcat);
        hipLaunchKernelGGL(bxd_bf16, dim3(MB * 2, BSZ / BM), dim3(256), 0, stream,
                           xbuf, wcat, out);
    } else {
        dim3 grid(MB * 2, BSZ / BM, 1);
        dim3 block(256, 1, 1);
        hipLaunchKernelGGL(bxd_kernel, grid, block, 0, stream,
                           x, Wd, Wu, Wl, Wtr, Wbl, out);
    }
}

// Round 3
// 658.834 us; speedup vs baseline: 1.1687x; 1.0579x over previous
//
#include <hip/hip_runtime.h>

// BlockXDiag forward: 64 GEMMs of [4096 x 768] x [768 x 256] (periodic block-tridiag).
// V3: pre-convert x/W to bf16 (unchanged), then 256x256-tile BK=64 GEMM:
//   - 512 threads (8 waves, 2M x 4N), acc 128x64 per wave
//   - double-buffered LDS (128 KiB), stage(next) issued before compute(cur),
//     single __syncthreads per K-step (T3 minimum 2-phase)
//   - T2 XOR-swizzle byte^=(row&7)<<4 on LDS, applied via pre-swizzled global
//     source (global_load_lds dest stays linear) + swizzled ds_read
//   - XCD-aware block mapping: each XCD owns 8 block-columns; weights stay L2-resident
// Falls back to V1 fp32-staging kernel if workspace too small.

#define MB   64      // blocks per row/col
#define PB   256     // block size
#define NPR  16384   // MB*PB, row stride of x/out
#define BSZ  4096    // batch
#define BM   256
#define BN   256
#define BK   64
#define KTILES 12    // 768 / BK
#define KTOT 768

typedef __bf16 bf16x8 __attribute__((ext_vector_type(8)));
typedef float  f32x4  __attribute__((ext_vector_type(4)));
typedef unsigned short u16x4 __attribute__((ext_vector_type(4)));
typedef unsigned short u16x8 __attribute__((ext_vector_type(8)));

__device__ __forceinline__ unsigned short f2bf(float f) {
    unsigned u = __float_as_uint(f);
    u += 0x7fffu + ((u >> 16) & 1u);   // round-to-nearest-even
    return (unsigned short)(u >> 16);
}

__device__ __forceinline__ void gload_lds16(const void* g, void* l) {
    __builtin_amdgcn_global_load_lds(
        (const __attribute__((address_space(1))) void*)g,
        (__attribute__((address_space(3))) void*)l, 16, 0, 0);
}

// ---------------- conversion pass 1: x (f32) -> xb (bf16) -------------------
__global__ __launch_bounds__(256)
void cvt_x(const float* __restrict__ in, __bf16* __restrict__ o, int n8) {
    int idx    = blockIdx.x * 256 + threadIdx.x;
    int stride = gridDim.x * 256;
    for (; idx < n8; idx += stride) {
        const float4* p = (const float4*)in + (size_t)idx * 2;
        float4 a = p[0], b = p[1];
        u16x8 r = { f2bf(a.x), f2bf(a.y), f2bf(a.z), f2bf(a.w),
                    f2bf(b.x), f2bf(b.y), f2bf(b.z), f2bf(b.w) };
        *((u16x8*)o + idx) = r;
    }
}

// -------- conversion pass 2: gather W into wcat[i][c][n][k] (bf16) ----------
__global__ __launch_bounds__(256)
void cvt_w(const float* __restrict__ Wd, const float* __restrict__ Wu,
           const float* __restrict__ Wl, const float* __restrict__ Wtr,
           const float* __restrict__ Wbl, __bf16* __restrict__ wcat) {
    const int i = blockIdx.y;
    const int c = blockIdx.z;
    const float* src;
    if      (c == 0) src = (i == 0)      ? Wtr : Wl + (size_t)(i - 1) * (PB * PB);
    else if (c == 1) src = Wd + (size_t)i * (PB * PB);
    else             src = (i == MB - 1) ? Wbl : Wu + (size_t)i * (PB * PB);

    const int off = (blockIdx.x * 256 + threadIdx.x) * 8;
    const float4* p = (const float4*)(src + off);
    float4 a = p[0], b = p[1];
    u16x8 r = { f2bf(a.x), f2bf(a.y), f2bf(a.z), f2bf(a.w),
                f2bf(b.x), f2bf(b.y), f2bf(b.z), f2bf(b.w) };
    *(u16x8*)(wcat + (size_t)(i * 3 + c) * (PB * PB) + off) = r;
}

// ---------------- main bf16 GEMM: 256x256, BK=64, dbuf 2-phase --------------
__global__ __launch_bounds__(512, 2)
void bxd_bf16(const __bf16* __restrict__ xb, const __bf16* __restrict__ wcat,
              float* __restrict__ out)
{
    // [buf][row][k]: row stride 128 B, linear dest for global_load_lds.
    __shared__ __bf16 sA[2][BM * BK];   // 2 x 32 KiB
    __shared__ __bf16 sB[2][BN * BK];   // 2 x 32 KiB

    // XCD-aware mapping: bid%8 = XCD (HW round-robin); each XCD owns 8 block
    // columns, iterating their 16 m-tiles -> weights (384 KB/col) stay in L2.
    const int bid  = blockIdx.x;        // 0..1023
    const int slot = bid >> 3;          // 0..127
    const int i    = (bid & 7) * 8 + (slot >> 4);   // block column 0..63
    const int mt   = slot & 15;                     // m-tile 0..15

    const int t    = threadIdx.x;
    const int lane = t & 63;
    const int wave = t >> 6;            // 0..7
    const int wm   = wave & 1;          // 2 waves in M
    const int wn   = wave >> 1;         // 4 waves in N
    const int quad = lane >> 4;
    const int l16  = lane & 15;

    const int jblk[3] = { (i + MB - 1) & (MB - 1), i, (i + 1) & (MB - 1) };

    // staging: 2048 16B-chunks per matrix per K-tile; thread t takes chunks
    // t + p*512 (p=0..3). row = chunk>>3 (128 B/row), chunkcol = chunk&7.
    // Swizzle LDS[row][col8 ^ (row&7)] <- pre-swizzle the SOURCE column.
    const int rowS   = t >> 3;                         // base row 0..63 (+p*64)
    const int srcoff = (((t & 7) ^ (rowS & 7))) * 8;   // bf16 elems, const in p

    // ds_read swizzled byte col: ((kh*4+quad) ^ (l16&7)) * 16 bytes -> *8 elems
    const int swz   = l16 & 7;
    const int colE0 = ((quad)     ^ swz) * 8;          // khalf 0
    const int colE1 = ((4 + quad) ^ swz) * 8;          // khalf 1
    const int arow  = wm * 128 + l16;                  // + mi*16
    const int brow  = wn * 64  + l16;                  // + ni*16

    f32x4 acc[8][4];
    #pragma unroll
    for (int a = 0; a < 8; ++a)
        #pragma unroll
        for (int b = 0; b < 4; ++b)
            acc[a][b] = (f32x4){0.f, 0.f, 0.f, 0.f};

    // ---- stage K-tile kt into buffer b ----
    auto stage = [&](int b, int kt) {
        const int c  = kt >> 2;        // P-chunk 0..2
        const int kb = kt & 3;         // BK-tile within chunk
        const __bf16* aB = xb + (size_t)(mt * BM) * NPR + jblk[c] * PB + kb * BK;
        const __bf16* bB = wcat + (size_t)(i * 3 + c) * (PB * PB) + kb * BK;
        #pragma unroll
        for (int p = 0; p < 4; ++p) {
            const int r = rowS + p * 64;
            gload_lds16(aB + (size_t)r * NPR + srcoff, &sA[b][(t + p * 512) * 8]);
            gload_lds16(bB + (size_t)r * PB  + srcoff, &sB[b][(t + p * 512) * 8]);
        }
    };

    stage(0, 0);
    __syncthreads();                    // drains vmcnt -> tile 0 visible

    int buf = 0;
    for (int kt = 0; kt < KTILES; ++kt) {
        if (kt + 1 < KTILES) stage(buf ^ 1, kt + 1);   // async prefetch

        #pragma unroll
        for (int kh = 0; kh < 2; ++kh) {
            const int colE = kh ? colE1 : colE0;
            bf16x8 af[8], bfr[4];
            #pragma unroll
            for (int mi = 0; mi < 8; ++mi)
                af[mi] = *(const bf16x8*)&sA[buf][(arow + mi * 16) * BK + colE];
            #pragma unroll
            for (int ni = 0; ni < 4; ++ni)
                bfr[ni] = *(const bf16x8*)&sB[buf][(brow + ni * 16) * BK + colE];

            __builtin_amdgcn_s_setprio(1);
            #pragma unroll
            for (int mi = 0; mi < 8; ++mi)
                #pragma unroll
                for (int ni = 0; ni < 4; ++ni)
                    acc[mi][ni] = __builtin_amdgcn_mfma_f32_16x16x32_bf16(
                        af[mi], bfr[ni], acc[mi][ni], 0, 0, 0);
            __builtin_amdgcn_s_setprio(0);
        }

        __syncthreads();   // drains vmcnt (prefetch done) + all reads consumed
        buf ^= 1;
    }

    // epilogue: C/D layout col = l16 (n), row = quad*4 + r (m)
    const int colb = i * PB + wn * 64;
    #pragma unroll
    for (int mi = 0; mi < 8; ++mi) {
        #pragma unroll
        for (int ni = 0; ni < 4; ++ni) {
            #pragma unroll
            for (int r = 0; r < 4; ++r) {
                const int row = mt * BM + wm * 128 + mi * 16 + quad * 4 + r;
                out[(size_t)row * NPR + colb + ni * 16 + l16] = acc[mi][ni][r];
            }
        }
    }
}

// ---------------- V1 fallback (fp32 staging, verified) ----------------------
__global__ __launch_bounds__(256, 2)
void bxd_kernel(const float* __restrict__ x,
                const float* __restrict__ Wd,
                const float* __restrict__ Wu,
                const float* __restrict__ Wl,
                const float* __restrict__ Wtr,
                const float* __restrict__ Wbl,
                float* __restrict__ out)
{
    __shared__ unsigned short sA[128 * 32];
    __shared__ unsigned short sB[128 * 32];

    const int i  = blockIdx.x >> 1;
    const int nt = blockIdx.x & 1;
    const int mt = blockIdx.y;

    const int t    = threadIdx.x;
    const int lane = t & 63;
    const int wave = t >> 6;
    const int wm   = wave & 1;
    const int wn   = wave >> 1;
    const int quad = lane >> 4;
    const int l16  = lane & 15;

    const int srow = t >> 3;
    const int scol = (t & 7) * 4;

    const float* wptr[3];
    wptr[0] = (i == 0)      ? Wtr : (Wl + (size_t)(i - 1) * (PB * PB));
    wptr[1] = Wd + (size_t)i * (PB * PB);
    wptr[2] = (i == MB - 1) ? Wbl : (Wu + (size_t)i * (PB * PB));
    const int jblk[3] = { (i + MB - 1) & (MB - 1), i, (i + 1) & (MB - 1) };

    f32x4 acc[4][4];
    #pragma unroll
    for (int a = 0; a < 4; ++a)
        #pragma unroll
        for (int b = 0; b < 4; ++b)
            acc[a][b] = (f32x4){0.f, 0.f, 0.f, 0.f};

    for (int kt = 0; kt < 24; ++kt) {
        const int c  = kt >> 3;
        const int kb = kt & 7;

        const float* aSrc = x + (size_t)(mt * 128 + srow) * NPR
                              + jblk[c] * PB + kb * 32 + scol;
        const float* bSrc = wptr[c] + (size_t)(nt * 128 + srow) * PB
                              + kb * 32 + scol;

        float4 av[4], bv[4];
        #pragma unroll
        for (int p = 0; p < 4; ++p) {
            av[p] = *(const float4*)(aSrc + (size_t)p * 32 * NPR);
            bv[p] = *(const float4*)(bSrc + (size_t)p * 32 * PB);
        }

        __syncthreads();
        #pragma unroll
        for (int p = 0; p < 4; ++p) {
            u16x4 ra = { f2bf(av[p].x), f2bf(av[p].y), f2bf(av[p].z), f2bf(av[p].w) };
            *(u16x4*)&sA[(srow + p * 32) * 32 + scol] = ra;
            u16x4 rb = { f2bf(bv[p].x), f2bf(bv[p].y), f2bf(bv[p].z), f2bf(bv[p].w) };
            *(u16x4*)&sB[(srow + p * 32) * 32 + scol] = rb;
        }
        __syncthreads();

        bf16x8 afrag[4], bfrag[4];
        #pragma unroll
        for (int mi = 0; mi < 4; ++mi)
            afrag[mi] = *(const bf16x8*)&sA[(wm * 64 + mi * 16 + l16) * 32 + quad * 8];
        #pragma unroll
        for (int ni = 0; ni < 4; ++ni)
            bfrag[ni] = *(const bf16x8*)&sB[(wn * 64 + ni * 16 + l16) * 32 + quad * 8];

        #pragma unroll
        for (int mi = 0; mi < 4; ++mi)
            #pragma unroll
            for (int ni = 0; ni < 4; ++ni)
                acc[mi][ni] = __builtin_amdgcn_mfma_f32_16x16x32_bf16(
                    afrag[mi], bfrag[ni], acc[mi][ni], 0, 0, 0);
    }

    const int colb = i * PB + nt * 128 + wn * 64;
    #pragma unroll
    for (int mi = 0; mi < 4; ++mi) {
        #pragma unroll
        for (int ni = 0; ni < 4; ++ni) {
            #pragma unroll
            for (int r = 0; r < 4; ++r) {
                const int row = mt * 128 + wm * 64 + mi * 16 + quad * 4 + r;
                out[(size_t)row * NPR + colb + ni * 16 + l16] = acc[mi][ni][r];
            }
        }
    }
}

extern "C" void kernel_launch(void* const* d_in, const int* in_sizes, int n_in,
                              void* d_out, int out_size, void* d_ws, size_t ws_size,
                              hipStream_t stream) {
    const float* x   = (const float*)d_in[0];
    const float* Wd  = (const float*)d_in[1];
    const float* Wu  = (const float*)d_in[2];
    const float* Wl  = (const float*)d_in[3];
    const float* Wtr = (const float*)d_in[4];
    const float* Wbl = (const float*)d_in[5];
    float* out = (float*)d_out;

    const size_t xbytes = (size_t)BSZ * NPR * sizeof(__bf16);        // 128 MiB
    const size_t wbytes = (size_t)MB * 3 * PB * PB * sizeof(__bf16); // 24 MiB

    if (ws_size >= xbytes + wbytes) {
        __bf16* xbuf = (__bf16*)d_ws;
        __bf16* wcat = (__bf16*)((char*)d_ws + xbytes);
        hipLaunchKernelGGL(cvt_x, dim3(2048), dim3(256), 0, stream,
                           x, xbuf, (int)((size_t)BSZ * NPR / 8));
        hipLaunchKernelGGL(cvt_w, dim3(32, 64, 3), dim3(256), 0, stream,
                           Wd, Wu, Wl, Wtr, Wbl, wcat);
        hipLaunchKernelGGL(bxd_bf16, dim3((MB) * (BSZ / BM)), dim3(512), 0, stream,
                           xbuf, wcat, out);
    } else {
        dim3 grid(MB * 2, BSZ / 128, 1);
        dim3 block(256, 1, 1);
        hipLaunchKernelGGL(bxd_kernel, grid, block, 0, stream,
                           x, Wd, Wu, Wl, Wtr, Wbl, out);
    }
}

// Round 4
// 655.484 us; speedup vs baseline: 1.1747x; 1.0051x over previous
//
#include <hip/hip_runtime.h>

// BlockXDiag forward: 64 GEMMs of [4096 x 768] x [768 x 256] (periodic block-tridiag).
// V4: V3 + T4 counted vmcnt. Main loop never drains vmcnt to 0:
//   iter t: stage(t+1 -> buf^1) ; s_waitcnt vmcnt(8)  [= tile t's loads done,
//   issued one full iteration earlier] ; s_barrier ; compute(buf) ; s_barrier.
//   Raw barriers (no compiler vmcnt(0) drain). Prologue/epilogue drain to 0.
// Keeps: bf16 pre-conversion, 256x256 tile BK=64, 8 waves (2Mx4N), T2 XOR
// swizzle (bank-conflict 0 in V3), XCD-aware mapping, T5 setprio.

#define MB   64      // blocks per row/col
#define PB   256     // block size
#define NPR  16384   // MB*PB, row stride of x/out
#define BSZ  4096    // batch
#define BM   256
#define BN   256
#define BK   64
#define KTILES 12    // 768 / BK

typedef __bf16 bf16x8 __attribute__((ext_vector_type(8)));
typedef float  f32x4  __attribute__((ext_vector_type(4)));
typedef unsigned short u16x4 __attribute__((ext_vector_type(4)));
typedef unsigned short u16x8 __attribute__((ext_vector_type(8)));

__device__ __forceinline__ unsigned short f2bf(float f) {
    unsigned u = __float_as_uint(f);
    u += 0x7fffu + ((u >> 16) & 1u);   // round-to-nearest-even
    return (unsigned short)(u >> 16);
}

__device__ __forceinline__ void gload_lds16(const void* g, void* l) {
    __builtin_amdgcn_global_load_lds(
        (const __attribute__((address_space(1))) void*)g,
        (__attribute__((address_space(3))) void*)l, 16, 0, 0);
}

// ---------------- conversion pass 1: x (f32) -> xb (bf16) -------------------
__global__ __launch_bounds__(256)
void cvt_x(const float* __restrict__ in, __bf16* __restrict__ o, int n8) {
    int idx    = blockIdx.x * 256 + threadIdx.x;
    int stride = gridDim.x * 256;
    for (; idx < n8; idx += stride) {
        const float4* p = (const float4*)in + (size_t)idx * 2;
        float4 a = p[0], b = p[1];
        u16x8 r = { f2bf(a.x), f2bf(a.y), f2bf(a.z), f2bf(a.w),
                    f2bf(b.x), f2bf(b.y), f2bf(b.z), f2bf(b.w) };
        *((u16x8*)o + idx) = r;
    }
}

// -------- conversion pass 2: gather W into wcat[i][c][n][k] (bf16) ----------
__global__ __launch_bounds__(256)
void cvt_w(const float* __restrict__ Wd, const float* __restrict__ Wu,
           const float* __restrict__ Wl, const float* __restrict__ Wtr,
           const float* __restrict__ Wbl, __bf16* __restrict__ wcat) {
    const int i = blockIdx.y;
    const int c = blockIdx.z;
    const float* src;
    if      (c == 0) src = (i == 0)      ? Wtr : Wl + (size_t)(i - 1) * (PB * PB);
    else if (c == 1) src = Wd + (size_t)i * (PB * PB);
    else             src = (i == MB - 1) ? Wbl : Wu + (size_t)i * (PB * PB);

    const int off = (blockIdx.x * 256 + threadIdx.x) * 8;
    const float4* p = (const float4*)(src + off);
    float4 a = p[0], b = p[1];
    u16x8 r = { f2bf(a.x), f2bf(a.y), f2bf(a.z), f2bf(a.w),
                f2bf(b.x), f2bf(b.y), f2bf(b.z), f2bf(b.w) };
    *(u16x8*)(wcat + (size_t)(i * 3 + c) * (PB * PB) + off) = r;
}

// ---------------- main bf16 GEMM: 256x256, BK=64, counted-vmcnt dbuf --------
__global__ __launch_bounds__(512, 2)
void bxd_bf16(const __bf16* __restrict__ xb, const __bf16* __restrict__ wcat,
              float* __restrict__ out)
{
    __shared__ __bf16 sA[2][BM * BK];   // 2 x 32 KiB, [buf][row][k] linear dest
    __shared__ __bf16 sB[2][BN * BK];   // 2 x 32 KiB

    // XCD-aware mapping: bid%8 = XCD; each XCD owns 8 block columns x 16 m-tiles.
    const int bid  = blockIdx.x;        // 0..1023
    const int slot = bid >> 3;          // 0..127
    const int i    = (bid & 7) * 8 + (slot >> 4);   // block column 0..63
    const int mt   = slot & 15;                     // m-tile 0..15

    const int t    = threadIdx.x;
    const int lane = t & 63;
    const int wave = t >> 6;            // 0..7
    const int wm   = wave & 1;          // 2 waves in M
    const int wn   = wave >> 1;         // 4 waves in N
    const int quad = lane >> 4;
    const int l16  = lane & 15;

    const int jblk[3] = { (i + MB - 1) & (MB - 1), i, (i + 1) & (MB - 1) };

    // staging: thread t takes 16B-chunks t + p*512 (p=0..3) of each matrix.
    // row = chunk>>3 (128 B/row). T2 swizzle via pre-swizzled SOURCE column.
    const int rowS   = t >> 3;                         // base row 0..63 (+p*64)
    const int srcoff = (((t & 7) ^ (rowS & 7))) * 8;   // bf16 elems

    // ds_read swizzled col: ((kh*4+quad) ^ (l16&7)) * 8 bf16 elems
    const int swz   = l16 & 7;
    const int colE0 = ((quad)     ^ swz) * 8;          // khalf 0
    const int colE1 = ((4 + quad) ^ swz) * 8;          // khalf 1
    const int arow  = wm * 128 + l16;                  // + mi*16
    const int brow  = wn * 64  + l16;                  // + ni*16

    f32x4 acc[8][4];
    #pragma unroll
    for (int a = 0; a < 8; ++a)
        #pragma unroll
        for (int b = 0; b < 4; ++b)
            acc[a][b] = (f32x4){0.f, 0.f, 0.f, 0.f};

    // stage K-tile kt into buffer b: 8 global_load_lds per thread (A:4, B:4)
    auto stage = [&](int b, int kt) {
        const int c  = kt >> 2;        // P-chunk 0..2
        const int kb = kt & 3;         // BK-tile within chunk
        const __bf16* aB = xb + (size_t)(mt * BM) * NPR + jblk[c] * PB + kb * BK;
        const __bf16* bB = wcat + (size_t)(i * 3 + c) * (PB * PB) + kb * BK;
        #pragma unroll
        for (int p = 0; p < 4; ++p) {
            const int r = rowS + p * 64;
            gload_lds16(aB + (size_t)r * NPR + srcoff, &sA[b][(t + p * 512) * 8]);
            gload_lds16(bB + (size_t)r * PB  + srcoff, &sB[b][(t + p * 512) * 8]);
        }
    };

    auto compute = [&](int b) {
        #pragma unroll
        for (int kh = 0; kh < 2; ++kh) {
            const int colE = kh ? colE1 : colE0;
            bf16x8 af[8], bfr[4];
            #pragma unroll
            for (int mi = 0; mi < 8; ++mi)
                af[mi] = *(const bf16x8*)&sA[b][(arow + mi * 16) * BK + colE];
            #pragma unroll
            for (int ni = 0; ni < 4; ++ni)
                bfr[ni] = *(const bf16x8*)&sB[b][(brow + ni * 16) * BK + colE];

            __builtin_amdgcn_s_setprio(1);
            #pragma unroll
            for (int mi = 0; mi < 8; ++mi)
                #pragma unroll
                for (int ni = 0; ni < 4; ++ni)
                    acc[mi][ni] = __builtin_amdgcn_mfma_f32_16x16x32_bf16(
                        af[mi], bfr[ni], acc[mi][ni], 0, 0, 0);
            __builtin_amdgcn_s_setprio(0);
        }
    };

    // prologue: tile 0 staged + drained
    stage(0, 0);
    asm volatile("s_waitcnt vmcnt(0)" ::: "memory");
    __builtin_amdgcn_sched_barrier(0);
    __builtin_amdgcn_s_barrier();

    int buf = 0;
    for (int kt = 0; kt < KTILES - 1; ++kt) {
        // overwrite of buf^1 is safe: last read in iter kt-1, behind barrier (2)
        stage(buf ^ 1, kt + 1);
        // tile kt's 8 loads are the only ones older than the 8 just issued
        asm volatile("s_waitcnt vmcnt(8)" ::: "memory");
        __builtin_amdgcn_sched_barrier(0);
        __builtin_amdgcn_s_barrier();            // (1) all waves' tile-kt loads visible
        __builtin_amdgcn_sched_barrier(0);
        compute(buf);
        __builtin_amdgcn_sched_barrier(0);
        __builtin_amdgcn_s_barrier();            // (2) all reads of buf done
        buf ^= 1;
    }
    // final tile: drain remaining 8 loads
    asm volatile("s_waitcnt vmcnt(0)" ::: "memory");
    __builtin_amdgcn_sched_barrier(0);
    __builtin_amdgcn_s_barrier();
    compute(buf);

    // epilogue: C/D layout col = l16 (n), row = quad*4 + r (m)
    const int colb = i * PB + wn * 64;
    #pragma unroll
    for (int mi = 0; mi < 8; ++mi) {
        #pragma unroll
        for (int ni = 0; ni < 4; ++ni) {
            #pragma unroll
            for (int r = 0; r < 4; ++r) {
                const int row = mt * BM + wm * 128 + mi * 16 + quad * 4 + r;
                out[(size_t)row * NPR + colb + ni * 16 + l16] = acc[mi][ni][r];
            }
        }
    }
}

// ---------------- V1 fallback (fp32 staging, verified) ----------------------
__global__ __launch_bounds__(256, 2)
void bxd_kernel(const float* __restrict__ x,
                const float* __restrict__ Wd,
                const float* __restrict__ Wu,
                const float* __restrict__ Wl,
                const float* __restrict__ Wtr,
                const float* __restrict__ Wbl,
                float* __restrict__ out)
{
    __shared__ unsigned short sA[128 * 32];
    __shared__ unsigned short sB[128 * 32];

    const int i  = blockIdx.x >> 1;
    const int nt = blockIdx.x & 1;
    const int mt = blockIdx.y;

    const int t    = threadIdx.x;
    const int lane = t & 63;
    const int wave = t >> 6;
    const int wm   = wave & 1;
    const int wn   = wave >> 1;
    const int quad = lane >> 4;
    const int l16  = lane & 15;

    const int srow = t >> 3;
    const int scol = (t & 7) * 4;

    const float* wptr[3];
    wptr[0] = (i == 0)      ? Wtr : (Wl + (size_t)(i - 1) * (PB * PB));
    wptr[1] = Wd + (size_t)i * (PB * PB);
    wptr[2] = (i == MB - 1) ? Wbl : (Wu + (size_t)i * (PB * PB));
    const int jblk[3] = { (i + MB - 1) & (MB - 1), i, (i + 1) & (MB - 1) };

    f32x4 acc[4][4];
    #pragma unroll
    for (int a = 0; a < 4; ++a)
        #pragma unroll
        for (int b = 0; b < 4; ++b)
            acc[a][b] = (f32x4){0.f, 0.f, 0.f, 0.f};

    for (int kt = 0; kt < 24; ++kt) {
        const int c  = kt >> 3;
        const int kb = kt & 7;

        const float* aSrc = x + (size_t)(mt * 128 + srow) * NPR
                              + jblk[c] * PB + kb * 32 + scol;
        const float* bSrc = wptr[c] + (size_t)(nt * 128 + srow) * PB
                              + kb * 32 + scol;

        float4 av[4], bv[4];
        #pragma unroll
        for (int p = 0; p < 4; ++p) {
            av[p] = *(const float4*)(aSrc + (size_t)p * 32 * NPR);
            bv[p] = *(const float4*)(bSrc + (size_t)p * 32 * PB);
        }

        __syncthreads();
        #pragma unroll
        for (int p = 0; p < 4; ++p) {
            u16x4 ra = { f2bf(av[p].x), f2bf(av[p].y), f2bf(av[p].z), f2bf(av[p].w) };
            *(u16x4*)&sA[(srow + p * 32) * 32 + scol] = ra;
            u16x4 rb = { f2bf(bv[p].x), f2bf(bv[p].y), f2bf(bv[p].z), f2bf(bv[p].w) };
            *(u16x4*)&sB[(srow + p * 32) * 32 + scol] = rb;
        }
        __syncthreads();

        bf16x8 afrag[4], bfrag[4];
        #pragma unroll
        for (int mi = 0; mi < 4; ++mi)
            afrag[mi] = *(const bf16x8*)&sA[(wm * 64 + mi * 16 + l16) * 32 + quad * 8];
        #pragma unroll
        for (int ni = 0; ni < 4; ++ni)
            bfrag[ni] = *(const bf16x8*)&sB[(wn * 64 + ni * 16 + l16) * 32 + quad * 8];

        #pragma unroll
        for (int mi = 0; mi < 4; ++mi)
            #pragma unroll
            for (int ni = 0; ni < 4; ++ni)
                acc[mi][ni] = __builtin_amdgcn_mfma_f32_16x16x32_bf16(
                    afrag[mi], bfrag[ni], acc[mi][ni], 0, 0, 0);
    }

    const int colb = i * PB + nt * 128 + wn * 64;
    #pragma unroll
    for (int mi = 0; mi < 4; ++mi) {
        #pragma unroll
        for (int ni = 0; ni < 4; ++ni) {
            #pragma unroll
            for (int r = 0; r < 4; ++r) {
                const int row = mt * 128 + wm * 64 + mi * 16 + quad * 4 + r;
                out[(size_t)row * NPR + colb + ni * 16 + l16] = acc[mi][ni][r];
            }
        }
    }
}

extern "C" void kernel_launch(void* const* d_in, const int* in_sizes, int n_in,
                              void* d_out, int out_size, void* d_ws, size_t ws_size,
                              hipStream_t stream) {
    const float* x   = (const float*)d_in[0];
    const float* Wd  = (const float*)d_in[1];
    const float* Wu  = (const float*)d_in[2];
    const float* Wl  = (const float*)d_in[3];
    const float* Wtr = (const float*)d_in[4];
    const float* Wbl = (const float*)d_in[5];
    float* out = (float*)d_out;

    const size_t xbytes = (size_t)BSZ * NPR * sizeof(__bf16);        // 128 MiB
    const size_t wbytes = (size_t)MB * 3 * PB * PB * sizeof(__bf16); // 24 MiB

    if (ws_size >= xbytes + wbytes) {
        __bf16* xbuf = (__bf16*)d_ws;
        __bf16* wcat = (__bf16*)((char*)d_ws + xbytes);
        hipLaunchKernelGGL(cvt_x, dim3(2048), dim3(256), 0, stream,
                           x, xbuf, (int)((size_t)BSZ * NPR / 8));
        hipLaunchKernelGGL(cvt_w, dim3(32, 64, 3), dim3(256), 0, stream,
                           Wd, Wu, Wl, Wtr, Wbl, wcat);
        hipLaunchKernelGGL(bxd_bf16, dim3(MB * (BSZ / BM)), dim3(512), 0, stream,
                           xbuf, wcat, out);
    } else {
        dim3 grid(MB * 2, BSZ / 128, 1);
        dim3 block(256, 1, 1);
        hipLaunchKernelGGL(bxd_kernel, grid, block, 0, stream,
                           x, Wd, Wu, Wl, Wtr, Wbl, out);
    }
}